// Round 1
// baseline (3344.867 us; speedup 1.0000x reference)
//
#include <hip/hip_runtime.h>

constexpr int N = 30000, E = 480000, G = 128, H = 4, D = 64;
constexpr int NF = 92, EF = 50, GF = 108, L = 5;
constexpr float EPS = 1e-3f;

__device__ __forceinline__ float lrelu(float t) { return t > 0.f ? t : 0.2f * t; }

// out[i,d] = lrelu(sum_k in[i,k]*W[k,d] + b[d]);  4 rows per block, wave per row
template <int K>
__global__ __launch_bounds__(256) void embed_kernel(
    const float* __restrict__ in, const float* __restrict__ W,
    const float* __restrict__ b, float* __restrict__ out, int rows) {
  int i = blockIdx.x * 4 + (threadIdx.x >> 6);
  int d = threadIdx.x & 63;
  if (i >= rows) return;
  const float* r = in + (size_t)i * K;
  float acc = b[d];
  for (int k = 0; k < K; k++) acc = fmaf(r[k], W[k * D + d], acc);
  out[(size_t)i * D + d] = lrelu(acc);
}

// Aes[k,h] = sum_d W[64+k, h*64+d] * (att[h,d] + att[h,64+d]);  one 256-thread block
__global__ __launch_bounds__(256) void aes_kernel(
    const float* __restrict__ W, const float* __restrict__ att, float* __restrict__ Aes) {
  int t = threadIdx.x;
  int k = t >> 2, h = t & 3;
  float acc = 0.f;
  for (int d = 0; d < D; d++)
    acc = fmaf(W[(64 + k) * 256 + h * 64 + d], att[h * 128 + d] + att[h * 128 + 64 + d], acc);
  Aes[k * 4 + h] = acc;
}

// per node: xW[n,0:256] = x[n,:] @ W[0:64,:]; pi[n,h]=sum_d xW*att[h,d]; pj: att[h,64+d]
__global__ __launch_bounds__(256) void xw_kernel(
    const float* __restrict__ xc, const float* __restrict__ W, const float* __restrict__ att,
    float* __restrict__ xW, float* __restrict__ pi, float* __restrict__ pj) {
  int n = blockIdx.x;
  int t = threadIdx.x;           // output column 0..255
  int h = t >> 6, dd = t & 63;   // wave w == head h
  const float* xr = xc + (size_t)n * D;
  float acc = 0.f;
  for (int k = 0; k < D; k++) acc = fmaf(xr[k], W[k * 256 + t], acc);
  xW[(size_t)n * 256 + t] = acc;
  float vi = acc * att[h * 128 + dd];
  float vj = acc * att[h * 128 + 64 + dd];
  for (int off = 32; off; off >>= 1) { vi += __shfl_down(vi, off); vj += __shfl_down(vj, off); }
  if (dd == 0) { pi[n * 4 + h] = vi; pj[n * 4 + h] = vj; }
}

// wave per edge: qs[h] = ea_emb[e]·Aes[:,h]; score = pi[row]+pj[col]+qs; a=exp(bn(lrelu));
__global__ __launch_bounds__(256) void score_kernel(
    const float* __restrict__ ea, const float* __restrict__ Aes,
    const float* __restrict__ pi, const float* __restrict__ pj,
    const int* __restrict__ row, const int* __restrict__ col,
    const float* __restrict__ bng, const float* __restrict__ bnb,
    const float* __restrict__ bnm, const float* __restrict__ bnv,
    float* __restrict__ aArr, float* __restrict__ normA) {
  int e = blockIdx.x * 4 + (threadIdx.x >> 6);
  int k = threadIdx.x & 63;
  float v = ea[(size_t)e * D + k];
  float4 A = ((const float4*)Aes)[k];
  float q0 = v * A.x, q1 = v * A.y, q2 = v * A.z, q3 = v * A.w;
  for (int off = 1; off < 64; off <<= 1) {
    q0 += __shfl_xor(q0, off); q1 += __shfl_xor(q1, off);
    q2 += __shfl_xor(q2, off); q3 += __shfl_xor(q3, off);
  }
  if (k < 4) {
    int re = row[e], ce = col[e];
    float qs = (k == 0) ? q0 : (k == 1) ? q1 : (k == 2) ? q2 : q3;
    float s = pi[re * 4 + k] + pj[ce * 4 + k] + qs;
    s = lrelu(s);
    s = (s - bnm[k]) * (1.f / sqrtf(bnv[k] + EPS)) * bng[k] + bnb[k];
    float a = expf(s);
    aArr[e * 4 + k] = a;
    atomicAdd(&normA[re * 4 + k], a);
  }
}

// a[e,h] /= norm[row[e],h]
__global__ __launch_bounds__(256) void norm_kernel(
    float* __restrict__ aArr, const float* __restrict__ normA, const int* __restrict__ row) {
  int e = blockIdx.x * blockDim.x + threadIdx.x;
  if (e >= E) return;
  int r = row[e];
  float4 a = ((float4*)aArr)[e];
  float4 nv = ((const float4*)normA)[r];
  a.x /= nv.x; a.y /= nv.y; a.z /= nv.z; a.w /= nv.w;
  ((float4*)aArr)[e] = a;
}

// slot r: q=4r..4r+3 -> edges e0..e0+3 at head h=(4r)/E, target=row[r].
// out1[v,d]  += sum_j a_j * xW[col[e_j], h*64+d]
// Bacc[v,h,k]+= sum_j a_j * ea_emb[e_j, k]
__global__ __launch_bounds__(256) void scatter_kernel(
    const float* __restrict__ aArr, const float* __restrict__ ea, const float* __restrict__ xW,
    const int* __restrict__ row, const int* __restrict__ col,
    float* __restrict__ out1, float* __restrict__ Bacc) {
  int wave = threadIdx.x >> 6, lane = threadIdx.x & 63;
  int r0 = blockIdx.x * 16 + wave * 4;
  for (int t = 0; t < 4; t++) {
    int r = r0 + t;
    int h = r / (E / 4);
    int e0 = 4 * r - h * E;
    int target = row[r];
    float m = 0.f, bs = 0.f;
#pragma unroll
    for (int j = 0; j < 4; j++) {
      float a = aArr[(e0 + j) * 4 + h];
      int cj = col[e0 + j];
      m = fmaf(a, xW[(size_t)cj * 256 + h * 64 + lane], m);
      bs = fmaf(a, ea[(size_t)(e0 + j) * 64 + lane], bs);
    }
    atomicAdd(&out1[target * 64 + lane], m);
    atomicAdd(&Bacc[(target * 4 + h) * 64 + lane], bs);
  }
}

// x[n,d] += bias[d] + 0.25*(out1[n,d] + sum_{h,k} B[n,h,k]*W[64+k, h*64+d])
__global__ __launch_bounds__(256) void finish_kernel(
    const float* __restrict__ out1, const float* __restrict__ Bacc,
    const float* __restrict__ W, const float* __restrict__ bias, float* __restrict__ xc) {
  int n = blockIdx.x * 4 + (threadIdx.x >> 6);
  int d = threadIdx.x & 63;
  const float* Bn = Bacc + (size_t)n * 256;
  float acc = 0.f;
  for (int hk = 0; hk < 256; hk++) {
    int h = hk >> 6, k = hk & 63;
    acc = fmaf(Bn[hk], W[(64 + k) * 256 + h * 64 + d], acc);
  }
  size_t idx = (size_t)n * 64 + d;
  xc[idx] = xc[idx] + bias[d] + 0.25f * (out1[idx] + acc);
}

// fused global-attention MLP per node: a_un[n]=exp(mlp(feat)); norm_g[graph]+=a_un
__global__ __launch_bounds__(256) void ga_node_kernel(
    const float* __restrict__ xc, const float* __restrict__ gf, const int* __restrict__ batch,
    const float* __restrict__ W0, const float* __restrict__ b0,
    const float* __restrict__ g0, const float* __restrict__ bb0,
    const float* __restrict__ m0, const float* __restrict__ v0,
    const float* __restrict__ W1, const float* __restrict__ b1,
    const float* __restrict__ g1, const float* __restrict__ bb1,
    const float* __restrict__ m1, const float* __restrict__ v1,
    const float* __restrict__ W2, const float* __restrict__ b2,
    float* __restrict__ a_un, float* __restrict__ norm_g) {
  int n = blockIdx.x * 4 + (threadIdx.x >> 6);
  int d = threadIdx.x & 63;
  const float* xr = xc + (size_t)n * 64;
  int b = batch[n];
  const float* gr = gf + (size_t)b * GF;
  float acc = b0[d];
  for (int k = 0; k < 64; k++) acc = fmaf(xr[k], W0[k * 64 + d], acc);
  for (int k = 0; k < GF; k++) acc = fmaf(gr[k], W0[(64 + k) * 64 + d], acc);
  float h0 = (acc - m0[d]) * (1.f / sqrtf(v0[d] + EPS)) * g0[d] + bb0[d];
  h0 = fmaxf(h0, 0.f);
  float acc1 = b1[d];
  for (int k = 0; k < 64; k++) acc1 = fmaf(__shfl(h0, k), W1[k * 64 + d], acc1);
  float h1 = (acc1 - m1[d]) * (1.f / sqrtf(v1[d] + EPS)) * g1[d] + bb1[d];
  h1 = fmaxf(h1, 0.f);
  float p = h1 * W2[d];
  for (int off = 1; off < 64; off <<= 1) p += __shfl_xor(p, off);
  if (d == 0) {
    float a = expf(p + b2[0]);
    a_un[n] = a;
    atomicAdd(&norm_g[b], a);
  }
}

// pooled[g,d] += x[n,d] * a_un[n]/norm_g[g]
__global__ __launch_bounds__(256) void pool_kernel(
    const float* __restrict__ xc, const float* __restrict__ a_un,
    const float* __restrict__ norm_g, const int* __restrict__ batch,
    float* __restrict__ pooled) {
  int n = blockIdx.x * 4 + (threadIdx.x >> 6);
  int d = threadIdx.x & 63;
  int b = batch[n];
  float coef = a_un[n] / norm_g[b];
  atomicAdd(&pooled[b * 64 + d], xc[(size_t)n * 64 + d] * coef);
}

// out[g] = relu(pooled[g]@W0 + b0) @ W1 + b1
__global__ __launch_bounds__(256) void final_kernel(
    const float* __restrict__ pooled, const float* __restrict__ W0,
    const float* __restrict__ b0, const float* __restrict__ W1,
    const float* __restrict__ b1, float* __restrict__ out) {
  int g = blockIdx.x * 4 + (threadIdx.x >> 6);
  int d = threadIdx.x & 63;
  float pv = pooled[g * 64 + d];
  float acc = b0[d];
  for (int k = 0; k < 64; k++) acc = fmaf(__shfl(pv, k), W0[k * 64 + d], acc);
  acc = fmaxf(acc, 0.f);
  float p = acc * W1[d];
  for (int off = 1; off < 64; off <<= 1) p += __shfl_xor(p, off);
  if (d == 0) out[g] = p + b1[0];
}

extern "C" void kernel_launch(void* const* d_in, const int* in_sizes, int n_in,
                              void* d_out, int out_size, void* d_ws, size_t ws_size,
                              hipStream_t stream) {
  (void)in_sizes; (void)n_in; (void)out_size; (void)ws_size;
  const float* x_in    = (const float*)d_in[0];
  const float* ea_in   = (const float*)d_in[1];
  const float* gf      = (const float*)d_in[2];
  const float* node_W  = (const float*)d_in[3];
  const float* node_b  = (const float*)d_in[4];
  const float* edge_W  = (const float*)d_in[5];
  const float* edge_b  = (const float*)d_in[6];
  const float* conv_W  = (const float*)d_in[7];
  const float* conv_att= (const float*)d_in[8];
  const float* conv_bias=(const float*)d_in[9];
  const float* bn_g = (const float*)d_in[10];
  const float* bn_b = (const float*)d_in[11];
  const float* bn_m = (const float*)d_in[12];
  const float* bn_v = (const float*)d_in[13];
  const float* ga_W0 = (const float*)d_in[14]; const float* ga_b0 = (const float*)d_in[15];
  const float* ga0g = (const float*)d_in[16];  const float* ga0b = (const float*)d_in[17];
  const float* ga0m = (const float*)d_in[18];  const float* ga0v = (const float*)d_in[19];
  const float* ga_W1 = (const float*)d_in[20]; const float* ga_b1 = (const float*)d_in[21];
  const float* ga1g = (const float*)d_in[22];  const float* ga1b = (const float*)d_in[23];
  const float* ga1m = (const float*)d_in[24];  const float* ga1v = (const float*)d_in[25];
  const float* ga_W2 = (const float*)d_in[26]; const float* ga_b2 = (const float*)d_in[27];
  const float* out_W0 = (const float*)d_in[28]; const float* out_b0 = (const float*)d_in[29];
  const float* out_W1 = (const float*)d_in[30]; const float* out_b1 = (const float*)d_in[31];
  const int* eidx  = (const int*)d_in[32];
  const int* row   = eidx;
  const int* col   = eidx + E;
  const int* batch = (const int*)d_in[33];

  float* ws = (float*)d_ws;
  size_t off = 0;
  auto alloc = [&](size_t n) { float* p = ws + off; off += (n + 63) & ~(size_t)63; return p; };
  float* x_cur  = alloc((size_t)N * D);       // 7.7 MB
  float* ea_emb = alloc((size_t)E * D);       // 122.9 MB
  float* xW     = alloc((size_t)N * 256);     // 30.7 MB
  float* pi     = alloc((size_t)N * 4);
  float* pj     = alloc((size_t)N * 4);
  float* aArr   = alloc((size_t)E * 4);       // 7.7 MB
  float* normA  = alloc((size_t)N * 4);
  float* out1   = alloc((size_t)N * 64);      // 7.7 MB
  float* Bacc   = alloc((size_t)N * 256);     // 30.7 MB
  float* Aes    = alloc(256);
  float* a_un   = alloc(N);
  float* norm_g = alloc(G);
  float* pooled = alloc((size_t)G * 64);

  embed_kernel<NF><<<N / 4, 256, 0, stream>>>(x_in, node_W, node_b, x_cur, N);
  embed_kernel<EF><<<E / 4, 256, 0, stream>>>(ea_in, edge_W, edge_b, ea_emb, E);

  for (int l = 0; l < L; l++) {
    const float* W   = conv_W + (size_t)l * 128 * 256;
    const float* att = conv_att + (size_t)l * H * 128;
    aes_kernel<<<1, 256, 0, stream>>>(W, att, Aes);
    xw_kernel<<<N, 256, 0, stream>>>(x_cur, W, att, xW, pi, pj);
    hipMemsetAsync(normA, 0, (size_t)N * 4 * sizeof(float), stream);
    score_kernel<<<E / 4, 256, 0, stream>>>(ea_emb, Aes, pi, pj, row, col,
                                            bn_g + l * H, bn_b + l * H,
                                            bn_m + l * H, bn_v + l * H, aArr, normA);
    norm_kernel<<<(E + 255) / 256, 256, 0, stream>>>(aArr, normA, row);
    hipMemsetAsync(out1, 0, (size_t)N * 64 * sizeof(float), stream);
    hipMemsetAsync(Bacc, 0, (size_t)N * 256 * sizeof(float), stream);
    scatter_kernel<<<E / 16, 256, 0, stream>>>(aArr, ea_emb, xW, row, col, out1, Bacc);
    finish_kernel<<<N / 4, 256, 0, stream>>>(out1, Bacc, W, conv_bias + l * D, x_cur);
  }

  hipMemsetAsync(norm_g, 0, G * sizeof(float), stream);
  hipMemsetAsync(pooled, 0, (size_t)G * 64 * sizeof(float), stream);
  ga_node_kernel<<<N / 4, 256, 0, stream>>>(x_cur, gf, batch,
                                            ga_W0, ga_b0, ga0g, ga0b, ga0m, ga0v,
                                            ga_W1, ga_b1, ga1g, ga1b, ga1m, ga1v,
                                            ga_W2, ga_b2, a_un, norm_g);
  pool_kernel<<<N / 4, 256, 0, stream>>>(x_cur, a_un, norm_g, batch, pooled);
  final_kernel<<<G / 4, 256, 0, stream>>>(pooled, out_W0, out_b0, out_W1, out_b1,
                                          (float*)d_out);
}

// Round 3
// 1935.573 us; speedup vs baseline: 1.7281x; 1.7281x over previous
//
#include <hip/hip_runtime.h>

constexpr int N = 30000, E = 480000, G = 128, H = 4, D = 64;
constexpr int NF = 92, EF = 50, GF = 108, L = 5;
constexpr int EQ = E / 4;  // slots per head (120000)
constexpr float EPS = 1e-3f;

__device__ __forceinline__ float lrelu(float t) { return t > 0.f ? t : 0.2f * t; }

// ---------------- CSR build: edges/slots sorted by row ----------------
__global__ __launch_bounds__(256) void hist_kernel(const int* __restrict__ row,
                                                   int* __restrict__ deg) {
  int e = blockIdx.x * 256 + threadIdx.x;
  atomicAdd(&deg[row[e]], 1);
}

__global__ __launch_bounds__(1024) void scan_kernel(const int* __restrict__ deg,
                                                    int* __restrict__ start) {
  __shared__ int wsum[16];
  __shared__ int cbase;
  if (threadIdx.x == 0) cbase = 0;
  __syncthreads();
  int lane = threadIdx.x & 63, wave = threadIdx.x >> 6;
  for (int base = 0; base < N; base += 1024) {
    int i = base + (int)threadIdx.x;
    int v = (i < N) ? deg[i] : 0;
    int s = v;
#pragma unroll
    for (int off = 1; off < 64; off <<= 1) { int t = __shfl_up(s, off); if (lane >= off) s += t; }
    if (lane == 63) wsum[wave] = s;
    __syncthreads();
    if (wave == 0 && lane < 16) {
      int w = wsum[lane];
#pragma unroll
      for (int off = 1; off < 16; off <<= 1) { int t = __shfl_up(w, off); if (lane >= off) w += t; }
      wsum[lane] = w;
    }
    __syncthreads();
    int wbase = wave ? wsum[wave - 1] : 0;
    if (i < N) start[i] = cbase + wbase + (s - v);
    __syncthreads();
    if (threadIdx.x == 0) cbase += wsum[15];
    __syncthreads();
  }
  if (threadIdx.x == 0) start[N] = cbase;
}

__global__ __launch_bounds__(256) void fill_kernel(
    const int* __restrict__ row, const int* __restrict__ start, int* __restrict__ cur,
    int* __restrict__ eid_s) {
  int e = blockIdx.x * 256 + threadIdx.x;
  int r = row[e];
  int pos = start[r] + atomicAdd(&cur[r], 1);
  eid_s[pos] = e;
}

// ---------------- embedding: out[i,d] = lrelu(in[i,:]@W + b) ----------------
template <int K>
__global__ __launch_bounds__(256) void embed2_kernel(
    const float* __restrict__ in, const float* __restrict__ W,
    const float* __restrict__ bias, float* __restrict__ out) {
  __shared__ float xs[16 * K];
  int tid = threadIdx.x, blk = blockIdx.x;
  for (int f = tid; f < 16 * K; f += 256) xs[f] = in[(size_t)blk * 16 * K + f];
  int lane = tid & 63, wave = tid >> 6;
  float wreg[K];
#pragma unroll
  for (int k = 0; k < K; k++) wreg[k] = W[k * 64 + lane];
  __syncthreads();
  const float* x0 = &xs[(wave * 4 + 0) * K];
  const float* x1 = &xs[(wave * 4 + 1) * K];
  const float* x2 = &xs[(wave * 4 + 2) * K];
  const float* x3 = &xs[(wave * 4 + 3) * K];
  float a0 = 0.f, a1 = 0.f, a2 = 0.f, a3 = 0.f;
#pragma unroll
  for (int k = 0; k < K; k++) {
    float w = wreg[k];
    a0 = fmaf(x0[k], w, a0); a1 = fmaf(x1[k], w, a1);
    a2 = fmaf(x2[k], w, a2); a3 = fmaf(x3[k], w, a3);
  }
  float bb = bias[lane];
  size_t o = (size_t)(blk * 16 + wave * 4) * 64 + lane;
  out[o]       = lrelu(a0 + bb);
  out[o + 64]  = lrelu(a1 + bb);
  out[o + 128] = lrelu(a2 + bb);
  out[o + 192] = lrelu(a3 + bb);
}

// ---------------- per-layer tiny precompute ----------------
// AesT[h*64+k] = sum_d W[64+k, h*64+d] * (att[h,d]+att[h,64+d])
// Watt[k*8 + h*2 + ij] = sum_d W[k, h*64+d] * att[h, ij*64+d]
__global__ __launch_bounds__(256) void aes_watt_kernel(
    const float* __restrict__ W, const float* __restrict__ att,
    float* __restrict__ AesT, float* __restrict__ Watt) {
  int t = threadIdx.x;
  {
    int h = t >> 6, k = t & 63;
    float acc = 0.f;
    for (int d = 0; d < 64; d++)
      acc = fmaf(W[(64 + k) * 256 + h * 64 + d], att[h * 128 + d] + att[h * 128 + 64 + d], acc);
    AesT[h * 64 + k] = acc;
  }
  for (int idx = t; idx < 512; idx += 256) {
    int k = idx >> 3, hh = idx & 7;
    int h = hh >> 1, ij = hh & 1;
    float acc = 0.f;
    for (int d = 0; d < 64; d++)
      acc = fmaf(W[k * 256 + h * 64 + d], att[h * 128 + ij * 64 + d], acc);
    Watt[idx] = acc;
  }
}

// ---------------- xW = x@W[0:64,:]  (+ pi/pj via Watt) ----------------
__global__ __launch_bounds__(256) void xw_kernel(
    const float* __restrict__ xc, const float* __restrict__ W, const float* __restrict__ Watt,
    float* __restrict__ xW, float* __restrict__ pi, float* __restrict__ pj) {
  __shared__ float xs[1024];
  __shared__ float wl[512];
  int tid = threadIdx.x, blk = blockIdx.x, n0 = blk * 16;
  for (int f = tid; f < 1024; f += 256) xs[f] = xc[(size_t)n0 * 64 + f];
  for (int f = tid; f < 512; f += 256) wl[f] = Watt[f];
  __syncthreads();
  float acc[16];
#pragma unroll
  for (int n = 0; n < 16; n++) acc[n] = 0.f;
  for (int k = 0; k < 64; k++) {
    float wv = W[k * 256 + tid];
#pragma unroll
    for (int n = 0; n < 16; n++) acc[n] = fmaf(xs[n * 64 + k], wv, acc[n]);
  }
#pragma unroll
  for (int n = 0; n < 16; n++) xW[(size_t)(n0 + n) * 256 + tid] = acc[n];
  if (tid < 128) {
    int n = tid >> 3, hh = tid & 7;
    int h = hh >> 1, ij = hh & 1;
    float a = 0.f;
    for (int k = 0; k < 64; k++) a = fmaf(xs[n * 64 + k], wl[k * 8 + hh], a);
    float* dst = ij ? pj : pi;
    dst[(n0 + n) * 4 + h] = a;
  }
}

// ---------------- edge scores -> a = exp(bn(lrelu(score))), original order ----------------
__global__ __launch_bounds__(256) void score_kernel(
    const float* __restrict__ ea, const float* __restrict__ AesT,
    const float* __restrict__ pi, const float* __restrict__ pj,
    const int* __restrict__ row, const int* __restrict__ col,
    const float* __restrict__ bng, const float* __restrict__ bnb,
    const float* __restrict__ bnm, const float* __restrict__ bnv,
    float* __restrict__ aArr) {
  int tid = threadIdx.x;
  int i = blockIdx.x * 16 + (tid >> 4);
  int k4 = tid & 15;
  const float4 ev = *(const float4*)&ea[(size_t)i * 64 + k4 * 4];
  const float4 c0 = *(const float4*)&AesT[0 * 64 + k4 * 4];
  const float4 c1 = *(const float4*)&AesT[1 * 64 + k4 * 4];
  const float4 c2 = *(const float4*)&AesT[2 * 64 + k4 * 4];
  const float4 c3 = *(const float4*)&AesT[3 * 64 + k4 * 4];
  float q0 = ev.x * c0.x + ev.y * c0.y + ev.z * c0.z + ev.w * c0.w;
  float q1 = ev.x * c1.x + ev.y * c1.y + ev.z * c1.z + ev.w * c1.w;
  float q2 = ev.x * c2.x + ev.y * c2.y + ev.z * c2.z + ev.w * c2.w;
  float q3 = ev.x * c3.x + ev.y * c3.y + ev.z * c3.z + ev.w * c3.w;
#pragma unroll
  for (int off = 1; off < 16; off <<= 1) {
    q0 += __shfl_xor(q0, off); q1 += __shfl_xor(q1, off);
    q2 += __shfl_xor(q2, off); q3 += __shfl_xor(q3, off);
  }
  int sub = tid & 15;
  if (sub < 4) {
    int h = sub;
    float qs = h == 0 ? q0 : h == 1 ? q1 : h == 2 ? q2 : q3;
    int r = row[i], c = col[i];
    float s = pi[r * 4 + h] + pj[c * 4 + h] + qs;
    s = lrelu(s);
    s = (s - bnm[h]) * rsqrtf(bnv[h] + EPS) * bng[h] + bnb[h];
    aArr[(size_t)i * 4 + h] = expf(s);
  }
}

// ---------------- softmax denom per (node,h) via CSR, no atomics ----------------
__global__ __launch_bounds__(256) void normsum_kernel(
    const float* __restrict__ aArr, const int* __restrict__ start,
    const int* __restrict__ eid_s, float* __restrict__ inv) {
  int n = blockIdx.x * 256 + threadIdx.x;
  if (n >= N) return;
  int s0 = start[n], s1 = start[n + 1];
  float4 s = {0.f, 0.f, 0.f, 0.f};
  for (int p = s0; p < s1; p++) {
    float4 a = ((const float4*)aArr)[eid_s[p]];
    s.x += a.x; s.y += a.y; s.z += a.z; s.w += a.w;
  }
  float4 iv;
  if (s1 > s0) { iv.x = 1.f / s.x; iv.y = 1.f / s.y; iv.z = 1.f / s.z; iv.w = 1.f / s.w; }
  else         { iv.x = iv.y = iv.z = iv.w = 0.f; }
  ((float4*)inv)[n] = iv;
}

// ---------------- normalize by row[e] and transpose a -> aT[h][e] ----------------
__global__ __launch_bounds__(256) void div_kernel(
    const float* __restrict__ aArr, const float* __restrict__ inv,
    const int* __restrict__ row, float* __restrict__ aT) {
  int e = blockIdx.x * 256 + threadIdx.x;
  float4 a = ((const float4*)aArr)[e];
  float4 iv = ((const float4*)inv)[row[e]];
  aT[0 * E + e] = a.x * iv.x;
  aT[1 * E + e] = a.y * iv.y;
  aT[2 * E + e] = a.z * iv.z;
  aT[3 * E + e] = a.w * iv.w;
}

// ---------------- scrambled scatter, wave per node, no atomics ----------------
// slot r (in [0,E)): head h = r/EQ, edges e0..e0+3 with e0 = 4*(r - h*EQ),
// target node = row[r]. CSR segment of n enumerates exactly {r : row[r]=n}.
__global__ __launch_bounds__(256) void scatter_kernel(
    const float* __restrict__ aT, const float* __restrict__ ea, const float* __restrict__ xW,
    const int* __restrict__ start, const int* __restrict__ eid_s, const int* __restrict__ col,
    float* __restrict__ out1, float* __restrict__ Bacc) {
  int wave = threadIdx.x >> 6, lane = threadIdx.x & 63;
  int n = blockIdx.x * 4 + wave;
  int s0 = start[n], s1 = start[n + 1];
  float m0 = 0.f, m1 = 0.f, m2 = 0.f, m3 = 0.f;
  float b0 = 0.f, b1 = 0.f, b2 = 0.f, b3 = 0.f;
  for (int p = s0; p < s1; p++) {
    int r = eid_s[p];
    int h = r / EQ;
    int e0 = (r - h * EQ) * 4;
    float4 a = *(const float4*)&aT[(size_t)h * E + e0];
    int4 c = *(const int4*)&col[e0];
    const float* xwh = xW + (size_t)h * 64 + lane;
    m0 = fmaf(a.x, xwh[(size_t)c.x * 256], m0);
    m1 = fmaf(a.y, xwh[(size_t)c.y * 256], m1);
    m2 = fmaf(a.z, xwh[(size_t)c.z * 256], m2);
    m3 = fmaf(a.w, xwh[(size_t)c.w * 256], m3);
    const float* er = ea + (size_t)e0 * 64 + lane;
    float s = a.x * er[0] + a.y * er[64] + a.z * er[128] + a.w * er[192];
    if (h == 0) b0 += s; else if (h == 1) b1 += s; else if (h == 2) b2 += s; else b3 += s;
  }
  out1[(size_t)n * 64 + lane] = (m0 + m1) + (m2 + m3);
  float* Bn = Bacc + (size_t)n * 256 + lane;
  Bn[0] = b0; Bn[64] = b1; Bn[128] = b2; Bn[192] = b3;
}

// ---------------- finish: x += bias + 0.25*(out1 + B@W_e) ----------------
__global__ __launch_bounds__(256) void finish_kernel(
    const float* __restrict__ out1, const float* __restrict__ Bacc,
    const float* __restrict__ W, const float* __restrict__ bias, float* __restrict__ xc) {
  __shared__ float Bl[4096];
  int tid = threadIdx.x, blk = blockIdx.x;
  for (int f = tid; f < 4096; f += 256) Bl[f] = Bacc[(size_t)blk * 4096 + f];
  __syncthreads();
  int lane = tid & 63, wave = tid >> 6;
  const float* B0 = &Bl[(wave * 4 + 0) * 256];
  const float* B1 = &Bl[(wave * 4 + 1) * 256];
  const float* B2 = &Bl[(wave * 4 + 2) * 256];
  const float* B3 = &Bl[(wave * 4 + 3) * 256];
  float a0 = 0.f, a1 = 0.f, a2 = 0.f, a3 = 0.f;
  for (int hk = 0; hk < 256; hk++) {
    float wv = W[(64 + (hk & 63)) * 256 + (hk >> 6) * 64 + lane];
    a0 = fmaf(B0[hk], wv, a0); a1 = fmaf(B1[hk], wv, a1);
    a2 = fmaf(B2[hk], wv, a2); a3 = fmaf(B3[hk], wv, a3);
  }
  float bb = bias[lane];
  size_t i0 = (size_t)(blk * 16 + wave * 4) * 64 + lane;
  xc[i0]       += bb + 0.25f * (out1[i0] + a0);
  xc[i0 + 64]  += bb + 0.25f * (out1[i0 + 64] + a1);
  xc[i0 + 128] += bb + 0.25f * (out1[i0 + 128] + a2);
  xc[i0 + 192] += bb + 0.25f * (out1[i0 + 192] + a3);
}

// ---------------- global attention MLP per node ----------------
__global__ __launch_bounds__(256) void ga_node_kernel(
    const float* __restrict__ xc, const float* __restrict__ gfeat, const int* __restrict__ batch,
    const float* __restrict__ W0, const float* __restrict__ b0,
    const float* __restrict__ g0, const float* __restrict__ bb0,
    const float* __restrict__ m0, const float* __restrict__ v0,
    const float* __restrict__ W1, const float* __restrict__ b1,
    const float* __restrict__ g1, const float* __restrict__ bb1,
    const float* __restrict__ m1, const float* __restrict__ v1,
    const float* __restrict__ W2, const float* __restrict__ b2,
    float* __restrict__ a_un, float* __restrict__ norm_g) {
  __shared__ float xs[1024];
  __shared__ float gfs[16 * GF];
  __shared__ int bl[16];
  int tid = threadIdx.x, blk = blockIdx.x, n0 = blk * 16;
  if (tid < 16) bl[tid] = batch[n0 + tid];
  __syncthreads();
  for (int f = tid; f < 1024; f += 256) xs[f] = xc[(size_t)n0 * 64 + f];
  for (int f = tid; f < 16 * GF; f += 256) {
    int r = f / GF, c = f - r * GF;
    gfs[f] = gfeat[(size_t)bl[r] * GF + c];
  }
  __syncthreads();
  int lane = tid & 63, wave = tid >> 6;
  const float* x0 = &xs[(wave * 4 + 0) * 64];
  const float* x1 = &xs[(wave * 4 + 1) * 64];
  const float* x2 = &xs[(wave * 4 + 2) * 64];
  const float* x3 = &xs[(wave * 4 + 3) * 64];
  const float* g0f = &gfs[(wave * 4 + 0) * GF];
  const float* g1f = &gfs[(wave * 4 + 1) * GF];
  const float* g2f = &gfs[(wave * 4 + 2) * GF];
  const float* g3f = &gfs[(wave * 4 + 3) * GF];
  float a0 = 0.f, a1 = 0.f, a2 = 0.f, a3 = 0.f;
  for (int k = 0; k < 64; k++) {
    float wv = W0[k * 64 + lane];
    a0 = fmaf(x0[k], wv, a0); a1 = fmaf(x1[k], wv, a1);
    a2 = fmaf(x2[k], wv, a2); a3 = fmaf(x3[k], wv, a3);
  }
  for (int k = 0; k < GF; k++) {
    float wv = W0[(64 + k) * 64 + lane];
    a0 = fmaf(g0f[k], wv, a0); a1 = fmaf(g1f[k], wv, a1);
    a2 = fmaf(g2f[k], wv, a2); a3 = fmaf(g3f[k], wv, a3);
  }
  float bb = b0[lane];
  float sc = rsqrtf(v0[lane] + EPS) * g0[lane];
  float mm = m0[lane], be = bb0[lane];
  float h00 = fmaxf((a0 + bb - mm) * sc + be, 0.f);
  float h01 = fmaxf((a1 + bb - mm) * sc + be, 0.f);
  float h02 = fmaxf((a2 + bb - mm) * sc + be, 0.f);
  float h03 = fmaxf((a3 + bb - mm) * sc + be, 0.f);
  float c0 = 0.f, c1 = 0.f, c2 = 0.f, c3 = 0.f;
  for (int k = 0; k < 64; k++) {
    float wv = W1[k * 64 + lane];
    c0 = fmaf(__shfl(h00, k), wv, c0); c1 = fmaf(__shfl(h01, k), wv, c1);
    c2 = fmaf(__shfl(h02, k), wv, c2); c3 = fmaf(__shfl(h03, k), wv, c3);
  }
  float bb1v = b1[lane];
  float sc1 = rsqrtf(v1[lane] + EPS) * g1[lane];
  float mm1 = m1[lane], be1 = bb1[lane];
  float w2 = W2[lane];
  float p0 = fmaxf((c0 + bb1v - mm1) * sc1 + be1, 0.f) * w2;
  float p1 = fmaxf((c1 + bb1v - mm1) * sc1 + be1, 0.f) * w2;
  float p2 = fmaxf((c2 + bb1v - mm1) * sc1 + be1, 0.f) * w2;
  float p3 = fmaxf((c3 + bb1v - mm1) * sc1 + be1, 0.f) * w2;
#pragma unroll
  for (int off = 1; off < 64; off <<= 1) {
    p0 += __shfl_xor(p0, off); p1 += __shfl_xor(p1, off);
    p2 += __shfl_xor(p2, off); p3 += __shfl_xor(p3, off);
  }
  if (lane < 4) {
    float pv = (lane == 0) ? p0 : (lane == 1) ? p1 : (lane == 2) ? p2 : p3;
    float a = expf(pv + b2[0]);
    int node = n0 + wave * 4 + lane;
    a_un[node] = a;
    atomicAdd(&norm_g[bl[wave * 4 + lane]], a);
  }
}

// ---------------- pooling & output ----------------
__global__ __launch_bounds__(256) void pool_kernel(
    const float* __restrict__ xc, const float* __restrict__ a_un,
    const float* __restrict__ norm_g, const int* __restrict__ batch,
    float* __restrict__ pooled) {
  int n = blockIdx.x * 4 + (threadIdx.x >> 6);
  int d = threadIdx.x & 63;
  int b = batch[n];
  float coef = a_un[n] / norm_g[b];
  atomicAdd(&pooled[b * 64 + d], xc[(size_t)n * 64 + d] * coef);
}

__global__ __launch_bounds__(256) void final_kernel(
    const float* __restrict__ pooled, const float* __restrict__ W0,
    const float* __restrict__ b0, const float* __restrict__ W1,
    const float* __restrict__ b1, float* __restrict__ out) {
  int g = blockIdx.x * 4 + (threadIdx.x >> 6);
  int d = threadIdx.x & 63;
  float pv = pooled[g * 64 + d];
  float acc = b0[d];
  for (int k = 0; k < 64; k++) acc = fmaf(__shfl(pv, k), W0[k * 64 + d], acc);
  acc = fmaxf(acc, 0.f);
  float p = acc * W1[d];
  for (int off = 1; off < 64; off <<= 1) p += __shfl_xor(p, off);
  if (d == 0) out[g] = p + b1[0];
}

extern "C" void kernel_launch(void* const* d_in, const int* in_sizes, int n_in,
                              void* d_out, int out_size, void* d_ws, size_t ws_size,
                              hipStream_t stream) {
  (void)in_sizes; (void)n_in; (void)out_size; (void)ws_size;
  const float* x_in    = (const float*)d_in[0];
  const float* ea_in   = (const float*)d_in[1];
  const float* gf      = (const float*)d_in[2];
  const float* node_W  = (const float*)d_in[3];
  const float* node_b  = (const float*)d_in[4];
  const float* edge_W  = (const float*)d_in[5];
  const float* edge_b  = (const float*)d_in[6];
  const float* conv_W  = (const float*)d_in[7];
  const float* conv_att= (const float*)d_in[8];
  const float* conv_bias=(const float*)d_in[9];
  const float* bn_g = (const float*)d_in[10];
  const float* bn_b = (const float*)d_in[11];
  const float* bn_m = (const float*)d_in[12];
  const float* bn_v = (const float*)d_in[13];
  const float* ga_W0 = (const float*)d_in[14]; const float* ga_b0 = (const float*)d_in[15];
  const float* ga0g = (const float*)d_in[16];  const float* ga0b = (const float*)d_in[17];
  const float* ga0m = (const float*)d_in[18];  const float* ga0v = (const float*)d_in[19];
  const float* ga_W1 = (const float*)d_in[20]; const float* ga_b1 = (const float*)d_in[21];
  const float* ga1g = (const float*)d_in[22];  const float* ga1b = (const float*)d_in[23];
  const float* ga1m = (const float*)d_in[24];  const float* ga1v = (const float*)d_in[25];
  const float* ga_W2 = (const float*)d_in[26]; const float* ga_b2 = (const float*)d_in[27];
  const float* out_W0 = (const float*)d_in[28]; const float* out_b0 = (const float*)d_in[29];
  const float* out_W1 = (const float*)d_in[30]; const float* out_b1 = (const float*)d_in[31];
  const int* eidx  = (const int*)d_in[32];
  const int* row   = eidx;
  const int* col   = eidx + E;
  const int* batch = (const int*)d_in[33];

  float* ws = (float*)d_ws;
  size_t off = 0;
  auto alloc = [&](size_t n) { float* p = ws + off; off += (n + 63) & ~(size_t)63; return p; };
  float* x_cur  = alloc((size_t)N * D);       // 7.7 MB
  float* ea_emb = alloc((size_t)E * D);       // 122.9 MB, original edge order
  float* xW     = alloc((size_t)N * 256);     // 30.7 MB
  float* pi     = alloc((size_t)N * 4);
  float* pj     = alloc((size_t)N * 4);
  float* aArr   = alloc((size_t)E * 4);       // 7.7 MB, original order
  float* aT     = alloc((size_t)E * 4);       // 7.7 MB, [h][e] normalized
  float* invA   = alloc((size_t)N * 4);
  float* out1   = alloc((size_t)N * 64);      // 7.7 MB
  float* Bacc   = alloc((size_t)N * 256);     // 30.7 MB
  float* AesT   = alloc(256);
  float* Watt   = alloc(512);
  float* a_un   = alloc(N);
  float* norm_g = alloc(G);
  float* pooled = alloc((size_t)G * 64);
  int* start = (int*)alloc(N + 1);
  int* eid_s = (int*)alloc(E);                // persistent — do NOT overlay
  // build-time scratch overlaid on xW (xW first written after CSR build)
  int* deg = (int*)xW;
  int* cur = deg + N;

  hipMemsetAsync(deg, 0, (size_t)2 * N * sizeof(int), stream);
  hist_kernel<<<E / 256, 256, 0, stream>>>(row, deg);
  scan_kernel<<<1, 1024, 0, stream>>>(deg, start);
  fill_kernel<<<E / 256, 256, 0, stream>>>(row, start, cur, eid_s);

  embed2_kernel<NF><<<N / 16, 256, 0, stream>>>(x_in, node_W, node_b, x_cur);
  embed2_kernel<EF><<<E / 16, 256, 0, stream>>>(ea_in, edge_W, edge_b, ea_emb);

  for (int l = 0; l < L; l++) {
    const float* W   = conv_W + (size_t)l * 128 * 256;
    const float* att = conv_att + (size_t)l * H * 128;
    aes_watt_kernel<<<1, 256, 0, stream>>>(W, att, AesT, Watt);
    xw_kernel<<<N / 16, 256, 0, stream>>>(x_cur, W, Watt, xW, pi, pj);
    score_kernel<<<E / 16, 256, 0, stream>>>(ea_emb, AesT, pi, pj, row, col,
                                             bn_g + l * H, bn_b + l * H,
                                             bn_m + l * H, bn_v + l * H, aArr);
    normsum_kernel<<<(N + 255) / 256, 256, 0, stream>>>(aArr, start, eid_s, invA);
    div_kernel<<<E / 256, 256, 0, stream>>>(aArr, invA, row, aT);
    scatter_kernel<<<N / 4, 256, 0, stream>>>(aT, ea_emb, xW, start, eid_s, col, out1, Bacc);
    finish_kernel<<<N / 16, 256, 0, stream>>>(out1, Bacc, W, conv_bias + l * D, x_cur);
  }

  hipMemsetAsync(norm_g, 0, G * sizeof(float), stream);
  hipMemsetAsync(pooled, 0, (size_t)G * 64 * sizeof(float), stream);
  ga_node_kernel<<<N / 16, 256, 0, stream>>>(x_cur, gf, batch,
                                             ga_W0, ga_b0, ga0g, ga0b, ga0m, ga0v,
                                             ga_W1, ga_b1, ga1g, ga1b, ga1m, ga1v,
                                             ga_W2, ga_b2, a_un, norm_g);
  pool_kernel<<<N / 4, 256, 0, stream>>>(x_cur, a_un, norm_g, batch, pooled);
  final_kernel<<<G / 4, 256, 0, stream>>>(pooled, out_W0, out_b0, out_W1, out_b1,
                                          (float*)d_out);
}

// Round 4
// 1865.794 us; speedup vs baseline: 1.7927x; 1.0374x over previous
//
#include <hip/hip_runtime.h>

constexpr int N = 30000, E = 480000, G = 128, H = 4, D = 64;
constexpr int NF = 92, EF = 50, GF = 108, L = 5;
constexpr int EQ = E / 4;  // slots per head (120000)
constexpr float EPS = 1e-3f;

__device__ __forceinline__ float lrelu(float t) { return t > 0.f ? t : 0.2f * t; }

// ---------------- CSR build: edges/slots sorted by row ----------------
__global__ __launch_bounds__(256) void hist_kernel(const int* __restrict__ row,
                                                   int* __restrict__ deg) {
  int e = blockIdx.x * 256 + threadIdx.x;
  atomicAdd(&deg[row[e]], 1);
}

__global__ __launch_bounds__(1024) void scan_kernel(const int* __restrict__ deg,
                                                    int* __restrict__ start) {
  __shared__ int wsum[16];
  __shared__ int cbase;
  if (threadIdx.x == 0) cbase = 0;
  __syncthreads();
  int lane = threadIdx.x & 63, wave = threadIdx.x >> 6;
  for (int base = 0; base < N; base += 1024) {
    int i = base + (int)threadIdx.x;
    int v = (i < N) ? deg[i] : 0;
    int s = v;
#pragma unroll
    for (int off = 1; off < 64; off <<= 1) { int t = __shfl_up(s, off); if (lane >= off) s += t; }
    if (lane == 63) wsum[wave] = s;
    __syncthreads();
    if (wave == 0 && lane < 16) {
      int w = wsum[lane];
#pragma unroll
      for (int off = 1; off < 16; off <<= 1) { int t = __shfl_up(w, off); if (lane >= off) w += t; }
      wsum[lane] = w;
    }
    __syncthreads();
    int wbase = wave ? wsum[wave - 1] : 0;
    if (i < N) start[i] = cbase + wbase + (s - v);
    __syncthreads();
    if (threadIdx.x == 0) cbase += wsum[15];
    __syncthreads();
  }
  if (threadIdx.x == 0) start[N] = cbase;
}

__global__ __launch_bounds__(256) void fill_kernel(
    const int* __restrict__ row, const int* __restrict__ start, int* __restrict__ cur,
    int* __restrict__ eid_s) {
  int e = blockIdx.x * 256 + threadIdx.x;
  int r = row[e];
  int pos = start[r] + atomicAdd(&cur[r], 1);
  eid_s[pos] = e;
}

// ---------------- embedding: out[i,d] = lrelu(in[i,:]@W + b) ----------------
// 16 rows/block in LDS (padded to x4); W column in regs; ds_read_b128 inner loop.
template <int K>
__global__ __launch_bounds__(256) void embed3_kernel(
    const float* __restrict__ in, const float* __restrict__ W,
    const float* __restrict__ bias, float* __restrict__ out) {
  constexpr int KP = (K + 3) & ~3;
  __shared__ float xs[16][KP];
  int tid = threadIdx.x, blk = blockIdx.x;
  for (int f = tid; f < 16 * KP; f += 256) {
    int r = f / KP, k = f - r * KP;
    xs[r][k] = (k < K) ? in[(size_t)blk * 16 * K + r * K + k] : 0.f;
  }
  int lane = tid & 63, wave = tid >> 6;
  float wreg[KP];
#pragma unroll
  for (int k = 0; k < K; k++) wreg[k] = W[k * 64 + lane];
#pragma unroll
  for (int k = K; k < KP; k++) wreg[k] = 0.f;
  __syncthreads();
  float a0 = 0.f, a1 = 0.f, a2 = 0.f, a3 = 0.f;
#pragma unroll
  for (int kc = 0; kc < KP / 4; kc++) {
    float4 x0 = *(const float4*)&xs[wave * 4 + 0][kc * 4];
    float4 x1 = *(const float4*)&xs[wave * 4 + 1][kc * 4];
    float4 x2 = *(const float4*)&xs[wave * 4 + 2][kc * 4];
    float4 x3 = *(const float4*)&xs[wave * 4 + 3][kc * 4];
    float w0 = wreg[kc * 4], w1 = wreg[kc * 4 + 1], w2 = wreg[kc * 4 + 2], w3 = wreg[kc * 4 + 3];
    a0 = fmaf(x0.x, w0, fmaf(x0.y, w1, fmaf(x0.z, w2, fmaf(x0.w, w3, a0))));
    a1 = fmaf(x1.x, w0, fmaf(x1.y, w1, fmaf(x1.z, w2, fmaf(x1.w, w3, a1))));
    a2 = fmaf(x2.x, w0, fmaf(x2.y, w1, fmaf(x2.z, w2, fmaf(x2.w, w3, a2))));
    a3 = fmaf(x3.x, w0, fmaf(x3.y, w1, fmaf(x3.z, w2, fmaf(x3.w, w3, a3))));
  }
  float bb = bias[lane];
  size_t o = (size_t)(blk * 16 + wave * 4) * 64 + lane;
  out[o]       = lrelu(a0 + bb);
  out[o + 64]  = lrelu(a1 + bb);
  out[o + 128] = lrelu(a2 + bb);
  out[o + 192] = lrelu(a3 + bb);
}

// ---------------- per-layer tiny precompute ----------------
// AesT[h*64+k] = sum_d W[64+k, h*64+d] * (att[h,d]+att[h,64+d])
// WattT[(h*2+ij)*64 + k] = sum_d W[k, h*64+d] * att[h, ij*64+d]
__global__ __launch_bounds__(256) void aes_watt_kernel(
    const float* __restrict__ W, const float* __restrict__ att,
    float* __restrict__ AesT, float* __restrict__ WattT) {
  int t = threadIdx.x;
  {
    int h = t >> 6, k = t & 63;
    float acc = 0.f;
    for (int d = 0; d < 64; d++)
      acc = fmaf(W[(64 + k) * 256 + h * 64 + d], att[h * 128 + d] + att[h * 128 + 64 + d], acc);
    AesT[h * 64 + k] = acc;
  }
  for (int idx = t; idx < 512; idx += 256) {
    int hh = idx >> 6, k = idx & 63;
    int h = hh >> 1, ij = hh & 1;
    float acc = 0.f;
    for (int d = 0; d < 64; d++)
      acc = fmaf(W[k * 256 + h * 64 + d], att[h * 128 + ij * 64 + d], acc);
    WattT[idx] = acc;
  }
}

// ---------------- xW = x@W[0:64,:]  (+ pi/pj via WattT) ----------------
__global__ __launch_bounds__(256) void xw_kernel(
    const float* __restrict__ xc, const float* __restrict__ W, const float* __restrict__ WattT,
    float* __restrict__ xW, float* __restrict__ pi, float* __restrict__ pj) {
  __shared__ float xs[16][64];
  __shared__ float wlT[8][68];
  int tid = threadIdx.x, blk = blockIdx.x, n0 = blk * 16;
  for (int f = tid; f < 1024; f += 256) xs[f >> 6][f & 63] = xc[(size_t)n0 * 64 + f];
  for (int f = tid; f < 512; f += 256) wlT[f >> 6][f & 63] = WattT[f];
  __syncthreads();
  float acc[16];
#pragma unroll
  for (int n = 0; n < 16; n++) acc[n] = 0.f;
#pragma unroll 4
  for (int kc = 0; kc < 16; kc++) {
    float w0 = W[(4 * kc + 0) * 256 + tid];
    float w1 = W[(4 * kc + 1) * 256 + tid];
    float w2 = W[(4 * kc + 2) * 256 + tid];
    float w3 = W[(4 * kc + 3) * 256 + tid];
#pragma unroll
    for (int n = 0; n < 16; n++) {
      float4 xv = *(const float4*)&xs[n][4 * kc];
      acc[n] = fmaf(xv.x, w0, fmaf(xv.y, w1, fmaf(xv.z, w2, fmaf(xv.w, w3, acc[n]))));
    }
  }
#pragma unroll
  for (int n = 0; n < 16; n++) xW[(size_t)(n0 + n) * 256 + tid] = acc[n];
  if (tid < 128) {
    int n = tid >> 3, hh = tid & 7;
    float a = 0.f;
#pragma unroll
    for (int kc = 0; kc < 16; kc++) {
      float4 xv = *(const float4*)&xs[n][4 * kc];
      float4 wv = *(const float4*)&wlT[hh][4 * kc];
      a = fmaf(xv.x, wv.x, fmaf(xv.y, wv.y, fmaf(xv.z, wv.z, fmaf(xv.w, wv.w, a))));
    }
    int h = hh >> 1, ij = hh & 1;
    float* dst = ij ? pj : pi;
    dst[(n0 + n) * 4 + h] = a;
  }
}

// ---------------- edge scores -> a = exp(bn(lrelu(score))), original order ----------------
__global__ __launch_bounds__(256) void score_kernel(
    const float* __restrict__ ea, const float* __restrict__ AesT,
    const float* __restrict__ pi, const float* __restrict__ pj,
    const int* __restrict__ row, const int* __restrict__ col,
    const float* __restrict__ bng, const float* __restrict__ bnb,
    const float* __restrict__ bnm, const float* __restrict__ bnv,
    float* __restrict__ aArr) {
  int tid = threadIdx.x;
  int i = blockIdx.x * 16 + (tid >> 4);
  int k4 = tid & 15;
  const float4 ev = *(const float4*)&ea[(size_t)i * 64 + k4 * 4];
  const float4 c0 = *(const float4*)&AesT[0 * 64 + k4 * 4];
  const float4 c1 = *(const float4*)&AesT[1 * 64 + k4 * 4];
  const float4 c2 = *(const float4*)&AesT[2 * 64 + k4 * 4];
  const float4 c3 = *(const float4*)&AesT[3 * 64 + k4 * 4];
  float q0 = ev.x * c0.x + ev.y * c0.y + ev.z * c0.z + ev.w * c0.w;
  float q1 = ev.x * c1.x + ev.y * c1.y + ev.z * c1.z + ev.w * c1.w;
  float q2 = ev.x * c2.x + ev.y * c2.y + ev.z * c2.z + ev.w * c2.w;
  float q3 = ev.x * c3.x + ev.y * c3.y + ev.z * c3.z + ev.w * c3.w;
#pragma unroll
  for (int off = 1; off < 16; off <<= 1) {
    q0 += __shfl_xor(q0, off); q1 += __shfl_xor(q1, off);
    q2 += __shfl_xor(q2, off); q3 += __shfl_xor(q3, off);
  }
  int sub = tid & 15;
  if (sub < 4) {
    int h = sub;
    float qs = h == 0 ? q0 : h == 1 ? q1 : h == 2 ? q2 : q3;
    int r = row[i], c = col[i];
    float s = pi[r * 4 + h] + pj[c * 4 + h] + qs;
    s = lrelu(s);
    s = (s - bnm[h]) * rsqrtf(bnv[h] + EPS) * bng[h] + bnb[h];
    aArr[(size_t)i * 4 + h] = expf(s);
  }
}

// ---------------- softmax denom per (node,h) via CSR, no atomics ----------------
__global__ __launch_bounds__(256) void normsum_kernel(
    const float* __restrict__ aArr, const int* __restrict__ start,
    const int* __restrict__ eid_s, float* __restrict__ inv) {
  int n = blockIdx.x * 256 + threadIdx.x;
  if (n >= N) return;
  int s0 = start[n], s1 = start[n + 1];
  float4 s = {0.f, 0.f, 0.f, 0.f};
  for (int p = s0; p < s1; p++) {
    float4 a = ((const float4*)aArr)[eid_s[p]];
    s.x += a.x; s.y += a.y; s.z += a.z; s.w += a.w;
  }
  float4 iv;
  if (s1 > s0) { iv.x = 1.f / s.x; iv.y = 1.f / s.y; iv.z = 1.f / s.z; iv.w = 1.f / s.w; }
  else         { iv.x = iv.y = iv.z = iv.w = 0.f; }
  ((float4*)inv)[n] = iv;
}

// ---------------- normalize by row[e] and transpose a -> aT[h][e] ----------------
__global__ __launch_bounds__(256) void div_kernel(
    const float* __restrict__ aArr, const float* __restrict__ inv,
    const int* __restrict__ row, float* __restrict__ aT) {
  int e = blockIdx.x * 256 + threadIdx.x;
  float4 a = ((const float4*)aArr)[e];
  float4 iv = ((const float4*)inv)[row[e]];
  aT[0 * E + e] = a.x * iv.x;
  aT[1 * E + e] = a.y * iv.y;
  aT[2 * E + e] = a.z * iv.z;
  aT[3 * E + e] = a.w * iv.w;
}

// ---------------- scrambled scatter, wave per node, no atomics ----------------
// slot r: head h = r/EQ, edges e0..e0+3 (e0=4*(r-h*EQ)), target row[r].
// 2-deep software pipeline for VMEM overlap.
__global__ __launch_bounds__(256) void scatter_kernel(
    const float* __restrict__ aT, const float* __restrict__ ea, const float* __restrict__ xW,
    const int* __restrict__ start, const int* __restrict__ eid_s, const int* __restrict__ col,
    float* __restrict__ out1, float* __restrict__ Bacc) {
  int wave = threadIdx.x >> 6, lane = threadIdx.x & 63;
  int n = blockIdx.x * 4 + wave;
  int s0 = start[n], s1 = start[n + 1];
  float m0 = 0.f, m1 = 0.f, m2 = 0.f, m3 = 0.f;
  float b0 = 0.f, b1 = 0.f, b2 = 0.f, b3 = 0.f;
  int p = s0;
  for (; p + 2 <= s1; p += 2) {
    int r1 = eid_s[p], r2 = eid_s[p + 1];
    int h1 = r1 / EQ, h2 = r2 / EQ;
    int e1 = (r1 - h1 * EQ) * 4, e2 = (r2 - h2 * EQ) * 4;
    float4 A1 = *(const float4*)&aT[(size_t)h1 * E + e1];
    float4 A2 = *(const float4*)&aT[(size_t)h2 * E + e2];
    int4 C1 = *(const int4*)&col[e1];
    int4 C2 = *(const int4*)&col[e2];
    const float* xw1 = xW + (size_t)h1 * 64 + lane;
    const float* xw2 = xW + (size_t)h2 * 64 + lane;
    const float* er1 = ea + (size_t)e1 * 64 + lane;
    const float* er2 = ea + (size_t)e2 * 64 + lane;
    float g10 = xw1[(size_t)C1.x * 256], g11 = xw1[(size_t)C1.y * 256];
    float g12 = xw1[(size_t)C1.z * 256], g13 = xw1[(size_t)C1.w * 256];
    float g20 = xw2[(size_t)C2.x * 256], g21 = xw2[(size_t)C2.y * 256];
    float g22 = xw2[(size_t)C2.z * 256], g23 = xw2[(size_t)C2.w * 256];
    float s1v = A1.x * er1[0] + A1.y * er1[64] + A1.z * er1[128] + A1.w * er1[192];
    float s2v = A2.x * er2[0] + A2.y * er2[64] + A2.z * er2[128] + A2.w * er2[192];
    m0 = fmaf(A1.x, g10, m0); m1 = fmaf(A1.y, g11, m1);
    m2 = fmaf(A1.z, g12, m2); m3 = fmaf(A1.w, g13, m3);
    m0 = fmaf(A2.x, g20, m0); m1 = fmaf(A2.y, g21, m1);
    m2 = fmaf(A2.z, g22, m2); m3 = fmaf(A2.w, g23, m3);
    if (h1 == 0) b0 += s1v; else if (h1 == 1) b1 += s1v; else if (h1 == 2) b2 += s1v; else b3 += s1v;
    if (h2 == 0) b0 += s2v; else if (h2 == 1) b1 += s2v; else if (h2 == 2) b2 += s2v; else b3 += s2v;
  }
  for (; p < s1; p++) {
    int r = eid_s[p];
    int h = r / EQ;
    int e0 = (r - h * EQ) * 4;
    float4 a = *(const float4*)&aT[(size_t)h * E + e0];
    int4 c = *(const int4*)&col[e0];
    const float* xwh = xW + (size_t)h * 64 + lane;
    m0 = fmaf(a.x, xwh[(size_t)c.x * 256], m0);
    m1 = fmaf(a.y, xwh[(size_t)c.y * 256], m1);
    m2 = fmaf(a.z, xwh[(size_t)c.z * 256], m2);
    m3 = fmaf(a.w, xwh[(size_t)c.w * 256], m3);
    const float* er = ea + (size_t)e0 * 64 + lane;
    float s = a.x * er[0] + a.y * er[64] + a.z * er[128] + a.w * er[192];
    if (h == 0) b0 += s; else if (h == 1) b1 += s; else if (h == 2) b2 += s; else b3 += s;
  }
  out1[(size_t)n * 64 + lane] = (m0 + m1) + (m2 + m3);
  float* Bn = Bacc + (size_t)n * 256 + lane;
  Bn[0] = b0; Bn[64] = b1; Bn[128] = b2; Bn[192] = b3;
}

// ---------------- finish: x += bias + 0.25*(out1 + B@W_e) ----------------
__global__ __launch_bounds__(256) void finish_kernel(
    const float* __restrict__ out1, const float* __restrict__ Bacc,
    const float* __restrict__ W, const float* __restrict__ bias, float* __restrict__ xc) {
  __shared__ float Bl[16][256];
  int tid = threadIdx.x, blk = blockIdx.x;
  for (int f = tid; f < 4096; f += 256) Bl[f >> 8][f & 255] = Bacc[(size_t)blk * 4096 + f];
  __syncthreads();
  int lane = tid & 63, wave = tid >> 6;
  float a0 = 0.f, a1 = 0.f, a2 = 0.f, a3 = 0.f;
#pragma unroll
  for (int h = 0; h < 4; h++) {
#pragma unroll 4
    for (int kc = 0; kc < 16; kc++) {
      float w0 = W[(64 + 4 * kc + 0) * 256 + h * 64 + lane];
      float w1 = W[(64 + 4 * kc + 1) * 256 + h * 64 + lane];
      float w2 = W[(64 + 4 * kc + 2) * 256 + h * 64 + lane];
      float w3 = W[(64 + 4 * kc + 3) * 256 + h * 64 + lane];
      float4 b0v = *(const float4*)&Bl[wave * 4 + 0][h * 64 + 4 * kc];
      float4 b1v = *(const float4*)&Bl[wave * 4 + 1][h * 64 + 4 * kc];
      float4 b2v = *(const float4*)&Bl[wave * 4 + 2][h * 64 + 4 * kc];
      float4 b3v = *(const float4*)&Bl[wave * 4 + 3][h * 64 + 4 * kc];
      a0 = fmaf(b0v.x, w0, fmaf(b0v.y, w1, fmaf(b0v.z, w2, fmaf(b0v.w, w3, a0))));
      a1 = fmaf(b1v.x, w0, fmaf(b1v.y, w1, fmaf(b1v.z, w2, fmaf(b1v.w, w3, a1))));
      a2 = fmaf(b2v.x, w0, fmaf(b2v.y, w1, fmaf(b2v.z, w2, fmaf(b2v.w, w3, a2))));
      a3 = fmaf(b3v.x, w0, fmaf(b3v.y, w1, fmaf(b3v.z, w2, fmaf(b3v.w, w3, a3))));
    }
  }
  float bb = bias[lane];
  size_t i0 = (size_t)(blk * 16 + wave * 4) * 64 + lane;
  xc[i0]       += bb + 0.25f * (out1[i0] + a0);
  xc[i0 + 64]  += bb + 0.25f * (out1[i0 + 64] + a1);
  xc[i0 + 128] += bb + 0.25f * (out1[i0 + 128] + a2);
  xc[i0 + 192] += bb + 0.25f * (out1[i0 + 192] + a3);
}

// ---------------- global attention MLP per node ----------------
__global__ __launch_bounds__(256) void ga_node_kernel(
    const float* __restrict__ xc, const float* __restrict__ gfeat, const int* __restrict__ batch,
    const float* __restrict__ W0, const float* __restrict__ b0,
    const float* __restrict__ g0, const float* __restrict__ bb0,
    const float* __restrict__ m0, const float* __restrict__ v0,
    const float* __restrict__ W1, const float* __restrict__ b1,
    const float* __restrict__ g1, const float* __restrict__ bb1,
    const float* __restrict__ m1, const float* __restrict__ v1,
    const float* __restrict__ W2, const float* __restrict__ b2,
    float* __restrict__ a_un, float* __restrict__ norm_g) {
  __shared__ float xs[16][64];
  __shared__ float gfs[16][GF];
  __shared__ int bl[16];
  int tid = threadIdx.x, blk = blockIdx.x, n0 = blk * 16;
  if (tid < 16) bl[tid] = batch[n0 + tid];
  __syncthreads();
  for (int f = tid; f < 1024; f += 256) xs[f >> 6][f & 63] = xc[(size_t)n0 * 64 + f];
  for (int f = tid; f < 16 * GF; f += 256) {
    int r = f / GF, c = f - r * GF;
    gfs[r][c] = gfeat[(size_t)bl[r] * GF + c];
  }
  __syncthreads();
  int lane = tid & 63, wave = tid >> 6;
  float a0 = 0.f, a1 = 0.f, a2 = 0.f, a3 = 0.f;
#pragma unroll 4
  for (int kc = 0; kc < 16; kc++) {
    float w0 = W0[(4 * kc + 0) * 64 + lane];
    float w1 = W0[(4 * kc + 1) * 64 + lane];
    float w2 = W0[(4 * kc + 2) * 64 + lane];
    float w3 = W0[(4 * kc + 3) * 64 + lane];
    float4 x0 = *(const float4*)&xs[wave * 4 + 0][4 * kc];
    float4 x1 = *(const float4*)&xs[wave * 4 + 1][4 * kc];
    float4 x2 = *(const float4*)&xs[wave * 4 + 2][4 * kc];
    float4 x3 = *(const float4*)&xs[wave * 4 + 3][4 * kc];
    a0 = fmaf(x0.x, w0, fmaf(x0.y, w1, fmaf(x0.z, w2, fmaf(x0.w, w3, a0))));
    a1 = fmaf(x1.x, w0, fmaf(x1.y, w1, fmaf(x1.z, w2, fmaf(x1.w, w3, a1))));
    a2 = fmaf(x2.x, w0, fmaf(x2.y, w1, fmaf(x2.z, w2, fmaf(x2.w, w3, a2))));
    a3 = fmaf(x3.x, w0, fmaf(x3.y, w1, fmaf(x3.z, w2, fmaf(x3.w, w3, a3))));
  }
#pragma unroll 3
  for (int kc = 0; kc < GF / 4; kc++) {
    float w0 = W0[(64 + 4 * kc + 0) * 64 + lane];
    float w1 = W0[(64 + 4 * kc + 1) * 64 + lane];
    float w2 = W0[(64 + 4 * kc + 2) * 64 + lane];
    float w3 = W0[(64 + 4 * kc + 3) * 64 + lane];
    float4 x0 = *(const float4*)&gfs[wave * 4 + 0][4 * kc];
    float4 x1 = *(const float4*)&gfs[wave * 4 + 1][4 * kc];
    float4 x2 = *(const float4*)&gfs[wave * 4 + 2][4 * kc];
    float4 x3 = *(const float4*)&gfs[wave * 4 + 3][4 * kc];
    a0 = fmaf(x0.x, w0, fmaf(x0.y, w1, fmaf(x0.z, w2, fmaf(x0.w, w3, a0))));
    a1 = fmaf(x1.x, w0, fmaf(x1.y, w1, fmaf(x1.z, w2, fmaf(x1.w, w3, a1))));
    a2 = fmaf(x2.x, w0, fmaf(x2.y, w1, fmaf(x2.z, w2, fmaf(x2.w, w3, a2))));
    a3 = fmaf(x3.x, w0, fmaf(x3.y, w1, fmaf(x3.z, w2, fmaf(x3.w, w3, a3))));
  }
  float bb = b0[lane];
  float sc = rsqrtf(v0[lane] + EPS) * g0[lane];
  float mm = m0[lane], be = bb0[lane];
  float h00 = fmaxf((a0 + bb - mm) * sc + be, 0.f);
  float h01 = fmaxf((a1 + bb - mm) * sc + be, 0.f);
  float h02 = fmaxf((a2 + bb - mm) * sc + be, 0.f);
  float h03 = fmaxf((a3 + bb - mm) * sc + be, 0.f);
  float c0 = 0.f, c1 = 0.f, c2 = 0.f, c3 = 0.f;
  for (int k = 0; k < 64; k++) {
    float wv = W1[k * 64 + lane];
    c0 = fmaf(__shfl(h00, k), wv, c0); c1 = fmaf(__shfl(h01, k), wv, c1);
    c2 = fmaf(__shfl(h02, k), wv, c2); c3 = fmaf(__shfl(h03, k), wv, c3);
  }
  float bb1v = b1[lane];
  float sc1 = rsqrtf(v1[lane] + EPS) * g1[lane];
  float mm1 = m1[lane], be1 = bb1[lane];
  float w2 = W2[lane];
  float p0 = fmaxf((c0 + bb1v - mm1) * sc1 + be1, 0.f) * w2;
  float p1 = fmaxf((c1 + bb1v - mm1) * sc1 + be1, 0.f) * w2;
  float p2 = fmaxf((c2 + bb1v - mm1) * sc1 + be1, 0.f) * w2;
  float p3 = fmaxf((c3 + bb1v - mm1) * sc1 + be1, 0.f) * w2;
#pragma unroll
  for (int off = 1; off < 64; off <<= 1) {
    p0 += __shfl_xor(p0, off); p1 += __shfl_xor(p1, off);
    p2 += __shfl_xor(p2, off); p3 += __shfl_xor(p3, off);
  }
  if (lane < 4) {
    float pv = (lane == 0) ? p0 : (lane == 1) ? p1 : (lane == 2) ? p2 : p3;
    float a = expf(pv + b2[0]);
    int node = n0 + wave * 4 + lane;
    a_un[node] = a;
    atomicAdd(&norm_g[bl[wave * 4 + lane]], a);
  }
}

// ---------------- pooling & output ----------------
__global__ __launch_bounds__(256) void pool_kernel(
    const float* __restrict__ xc, const float* __restrict__ a_un,
    const float* __restrict__ norm_g, const int* __restrict__ batch,
    float* __restrict__ pooled) {
  int n = blockIdx.x * 4 + (threadIdx.x >> 6);
  int d = threadIdx.x & 63;
  int b = batch[n];
  float coef = a_un[n] / norm_g[b];
  atomicAdd(&pooled[b * 64 + d], xc[(size_t)n * 64 + d] * coef);
}

__global__ __launch_bounds__(256) void final_kernel(
    const float* __restrict__ pooled, const float* __restrict__ W0,
    const float* __restrict__ b0, const float* __restrict__ W1,
    const float* __restrict__ b1, float* __restrict__ out) {
  int g = blockIdx.x * 4 + (threadIdx.x >> 6);
  int d = threadIdx.x & 63;
  float pv = pooled[g * 64 + d];
  float acc = b0[d];
  for (int k = 0; k < 64; k++) acc = fmaf(__shfl(pv, k), W0[k * 64 + d], acc);
  acc = fmaxf(acc, 0.f);
  float p = acc * W1[d];
  for (int off = 1; off < 64; off <<= 1) p += __shfl_xor(p, off);
  if (d == 0) out[g] = p + b1[0];
}

extern "C" void kernel_launch(void* const* d_in, const int* in_sizes, int n_in,
                              void* d_out, int out_size, void* d_ws, size_t ws_size,
                              hipStream_t stream) {
  (void)in_sizes; (void)n_in; (void)out_size; (void)ws_size;
  const float* x_in    = (const float*)d_in[0];
  const float* ea_in   = (const float*)d_in[1];
  const float* gf      = (const float*)d_in[2];
  const float* node_W  = (const float*)d_in[3];
  const float* node_b  = (const float*)d_in[4];
  const float* edge_W  = (const float*)d_in[5];
  const float* edge_b  = (const float*)d_in[6];
  const float* conv_W  = (const float*)d_in[7];
  const float* conv_att= (const float*)d_in[8];
  const float* conv_bias=(const float*)d_in[9];
  const float* bn_g = (const float*)d_in[10];
  const float* bn_b = (const float*)d_in[11];
  const float* bn_m = (const float*)d_in[12];
  const float* bn_v = (const float*)d_in[13];
  const float* ga_W0 = (const float*)d_in[14]; const float* ga_b0 = (const float*)d_in[15];
  const float* ga0g = (const float*)d_in[16];  const float* ga0b = (const float*)d_in[17];
  const float* ga0m = (const float*)d_in[18];  const float* ga0v = (const float*)d_in[19];
  const float* ga_W1 = (const float*)d_in[20]; const float* ga_b1 = (const float*)d_in[21];
  const float* ga1g = (const float*)d_in[22];  const float* ga1b = (const float*)d_in[23];
  const float* ga1m = (const float*)d_in[24];  const float* ga1v = (const float*)d_in[25];
  const float* ga_W2 = (const float*)d_in[26]; const float* ga_b2 = (const float*)d_in[27];
  const float* out_W0 = (const float*)d_in[28]; const float* out_b0 = (const float*)d_in[29];
  const float* out_W1 = (const float*)d_in[30]; const float* out_b1 = (const float*)d_in[31];
  const int* eidx  = (const int*)d_in[32];
  const int* row   = eidx;
  const int* col   = eidx + E;
  const int* batch = (const int*)d_in[33];

  float* ws = (float*)d_ws;
  size_t off = 0;
  auto alloc = [&](size_t n) { float* p = ws + off; off += (n + 63) & ~(size_t)63; return p; };
  float* x_cur  = alloc((size_t)N * D);       // 7.7 MB
  float* ea_emb = alloc((size_t)E * D);       // 122.9 MB, original edge order
  float* xW     = alloc((size_t)N * 256);     // 30.7 MB
  float* pi     = alloc((size_t)N * 4);
  float* pj     = alloc((size_t)N * 4);
  float* aArr   = alloc((size_t)E * 4);       // 7.7 MB, original order
  float* aT     = alloc((size_t)E * 4);       // 7.7 MB, [h][e] normalized
  float* invA   = alloc((size_t)N * 4);
  float* out1   = alloc((size_t)N * 64);      // 7.7 MB
  float* Bacc   = alloc((size_t)N * 256);     // 30.7 MB
  float* AesT   = alloc(256);
  float* WattT  = alloc(512);
  float* a_un   = alloc(N);
  float* norm_g = alloc(G);
  float* pooled = alloc((size_t)G * 64);
  int* start = (int*)alloc(N + 1);
  int* eid_s = (int*)alloc(E);                // persistent — do NOT overlay
  // build-time scratch overlaid on xW (xW first written after CSR build)
  int* deg = (int*)xW;
  int* cur = deg + N;

  hipMemsetAsync(deg, 0, (size_t)2 * N * sizeof(int), stream);
  hist_kernel<<<E / 256, 256, 0, stream>>>(row, deg);
  scan_kernel<<<1, 1024, 0, stream>>>(deg, start);
  fill_kernel<<<E / 256, 256, 0, stream>>>(row, start, cur, eid_s);

  embed3_kernel<NF><<<N / 16, 256, 0, stream>>>(x_in, node_W, node_b, x_cur);
  embed3_kernel<EF><<<E / 16, 256, 0, stream>>>(ea_in, edge_W, edge_b, ea_emb);

  for (int l = 0; l < L; l++) {
    const float* W   = conv_W + (size_t)l * 128 * 256;
    const float* att = conv_att + (size_t)l * H * 128;
    aes_watt_kernel<<<1, 256, 0, stream>>>(W, att, AesT, WattT);
    xw_kernel<<<N / 16, 256, 0, stream>>>(x_cur, W, WattT, xW, pi, pj);
    score_kernel<<<E / 16, 256, 0, stream>>>(ea_emb, AesT, pi, pj, row, col,
                                             bn_g + l * H, bn_b + l * H,
                                             bn_m + l * H, bn_v + l * H, aArr);
    normsum_kernel<<<(N + 255) / 256, 256, 0, stream>>>(aArr, start, eid_s, invA);
    div_kernel<<<E / 256, 256, 0, stream>>>(aArr, invA, row, aT);
    scatter_kernel<<<N / 4, 256, 0, stream>>>(aT, ea_emb, xW, start, eid_s, col, out1, Bacc);
    finish_kernel<<<N / 16, 256, 0, stream>>>(out1, Bacc, W, conv_bias + l * D, x_cur);
  }

  hipMemsetAsync(norm_g, 0, G * sizeof(float), stream);
  hipMemsetAsync(pooled, 0, (size_t)G * 64 * sizeof(float), stream);
  ga_node_kernel<<<N / 16, 256, 0, stream>>>(x_cur, gf, batch,
                                             ga_W0, ga_b0, ga0g, ga0b, ga0m, ga0v,
                                             ga_W1, ga_b1, ga1g, ga1b, ga1m, ga1v,
                                             ga_W2, ga_b2, a_un, norm_g);
  pool_kernel<<<N / 4, 256, 0, stream>>>(x_cur, a_un, norm_g, batch, pooled);
  final_kernel<<<G / 4, 256, 0, stream>>>(pooled, out_W0, out_b0, out_W1, out_b1,
                                          (float*)d_out);
}